// Round 1
// baseline (12384.251 us; speedup 1.0000x reference)
//
#include <hip/hip_runtime.h>
#include <hip/hip_bf16.h>

// ---------------- common helpers ----------------
typedef __attribute__((ext_vector_type(8))) short short8_t;
typedef __attribute__((ext_vector_type(4))) float f32x4_t;

__device__ __forceinline__ unsigned short f2bf(float f) {
    unsigned u = __float_as_uint(f);
    unsigned r = (u + 0x7FFFu + ((u >> 16) & 1u)) >> 16;
    return (unsigned short)r;
}
__device__ __forceinline__ float bf2f(unsigned short u) {
    return __uint_as_float(((unsigned)u) << 16);
}
__device__ __forceinline__ float sigm(float x) { return 1.f / (1.f + __expf(-x)); }
__device__ __forceinline__ float tanhfast(float x) {
    x = fminf(fmaxf(x, -15.f), 15.f);
    float e = __expf(2.f * x);
    return (e - 1.f) / (e + 1.f);
}

// dims
#define BATCH 64
#define SEQ 200
#define HID 512
#define G4 2048           // 4*HID
#define NLAB 66
#define START_L 64
#define STOP_L 65
#define KPAD 320          // 300 padded to mult of 64

// ---------------- K1: embed gather + max-norm scale -> bf16 A [12800][320] ----------------
// A row index = token = s*64 + b
__global__ __launch_bounds__(256) void embed_k(const int* __restrict__ data,
                                               const float* __restrict__ emb,
                                               unsigned short* __restrict__ A) {
    int w = threadIdx.x >> 6, l = threadIdx.x & 63;
    int tok = blockIdx.x * 4 + w;
    int s = tok >> 6, b = tok & 63;
    int row = data[b * SEQ + s];
    const float* src = emb + (size_t)row * 300;
    float vals[5];
    float ss = 0.f;
#pragma unroll
    for (int u = 0; u < 5; u++) {
        int e = l + u * 64;
        float v = (e < 300) ? src[e] : 0.f;
        vals[u] = v;
        ss += v * v;
    }
#pragma unroll
    for (int off = 1; off < 64; off <<= 1) ss += __shfl_xor(ss, off);
    float nrm = sqrtf(ss);
    float scale = fminf(1.f, 6.f / fmaxf(nrm, 1e-7f));
    unsigned short* dst = A + (size_t)tok * KPAD;
#pragma unroll
    for (int u = 0; u < 5; u++) {
        int e = l + u * 64;
        dst[e] = (e < 300) ? f2bf(vals[u] * scale) : (unsigned short)0;
    }
}

// ---------------- K2: W_ih fp32[2048][300] -> bf16 [2048][320] ----------------
__global__ void convw_k(const float* __restrict__ W, unsigned short* __restrict__ Wb) {
    int idx = blockIdx.x * blockDim.x + threadIdx.x;
    if (idx < G4 * KPAD) {
        int r = idx / KPAD, k = idx % KPAD;
        Wb[idx] = (k < 300) ? f2bf(W[r * 300 + k]) : (unsigned short)0;
    }
}

// ---------------- K3/K5: MFMA GEMM  C[m][n] = sum_k A[m][k]*B[n][k] ----------------
// MODE 0: x_proj: A=Wihb[2048][320] bf16, B=Aemb[12800][320] bf16, C=X bf16 [2048][12800]
// MODE 1: feats : A=W_fc fp32 [66][512] (converted, rows>=66 zero), B=HS [200][512][64] bf16
//                 (transposed staging), C=F fp32 [64][200][66] (+ b_fc bias)
template <int MODE>
__global__ __launch_bounds__(256) void gemm_k(const unsigned short* __restrict__ Abf,
                                              const float* __restrict__ Af32,
                                              const unsigned short* __restrict__ Bbf,
                                              unsigned short* __restrict__ Cbf,
                                              float* __restrict__ Cf32,
                                              const float* __restrict__ bias) {
    constexpr int KTOT = (MODE == 0) ? KPAD : HID;
    constexpr int NKT = KTOT / 64;
    const int bm = (MODE == 0) ? (blockIdx.x & 15) : 0;
    const int bn = (MODE == 0) ? (blockIdx.x >> 4) : blockIdx.x;
    const int m0 = bm * 128, n0 = bn * 128;
    __shared__ unsigned short Al[128 * 72];
    __shared__ unsigned short Bl[128 * 72];
    const int tid = threadIdx.x;
    const int w = tid >> 6, l = tid & 63;
    const int wr = w >> 1, wc = w & 1;
    f32x4_t acc[4][4];
#pragma unroll
    for (int i = 0; i < 4; i++)
#pragma unroll
        for (int j = 0; j < 4; j++) {
            acc[i][j].x = 0.f; acc[i][j].y = 0.f; acc[i][j].z = 0.f; acc[i][j].w = 0.f;
        }

    for (int kt = 0; kt < NKT; kt++) {
        // ---- stage A tile [128][64] ----
        {
            int row = tid >> 1, half = tid & 1;
            int kbase = kt * 64 + half * 32;
            if constexpr (MODE == 0) {
                const unsigned short* src = Abf + (size_t)(m0 + row) * KPAD + kbase;
#pragma unroll
                for (int q = 0; q < 4; q++)
                    *(short8_t*)&Al[row * 72 + half * 32 + q * 8] = *(const short8_t*)(src + q * 8);
            } else {
                if (row < NLAB) {
                    const float* src = Af32 + (size_t)row * HID + kbase;
#pragma unroll
                    for (int q = 0; q < 4; q++) {
                        short8_t o;
#pragma unroll
                        for (int x = 0; x < 8; x++) o[x] = (short)f2bf(src[q * 8 + x]);
                        *(short8_t*)&Al[row * 72 + half * 32 + q * 8] = o;
                    }
                } else {
                    short8_t z = {0, 0, 0, 0, 0, 0, 0, 0};
#pragma unroll
                    for (int q = 0; q < 4; q++)
                        *(short8_t*)&Al[row * 72 + half * 32 + q * 8] = z;
                }
            }
        }
        // ---- stage B tile [128][64] ----
        if constexpr (MODE == 0) {
            int row = tid >> 1, half = tid & 1;
            int kbase = kt * 64 + half * 32;
            const unsigned short* src = Bbf + (size_t)(n0 + row) * KPAD + kbase;
#pragma unroll
            for (int q = 0; q < 4; q++)
                *(short8_t*)&Bl[row * 72 + half * 32 + q * 8] = *(const short8_t*)(src + q * 8);
        } else {
            // HS layout [t][k][b]; tile tokens n0..n0+128 = s in {2bn, 2bn+1}, all 64 b
            int kk = tid >> 2, b0 = (tid & 3) * 16;
            int s0 = n0 >> 6;
#pragma unroll
            for (int sl = 0; sl < 2; sl++) {
                const unsigned short* src =
                    Bbf + ((size_t)(s0 + sl) * HID + kt * 64 + kk) * BATCH + b0;
                short8_t v0 = *(const short8_t*)src;
                short8_t v1 = *(const short8_t*)(src + 8);
#pragma unroll
                for (int x = 0; x < 8; x++) {
                    Bl[(sl * 64 + b0 + x) * 72 + kk] = (unsigned short)v0[x];
                    Bl[(sl * 64 + b0 + 8 + x) * 72 + kk] = (unsigned short)v1[x];
                }
            }
        }
        __syncthreads();
        // ---- MFMA ----
#pragma unroll
        for (int kk2 = 0; kk2 < 2; kk2++) {
            short8_t af[4], bfv[4];
#pragma unroll
            for (int i = 0; i < 4; i++)
                af[i] = *(const short8_t*)&Al[(wr * 64 + i * 16 + (l & 15)) * 72 + kk2 * 32 + (l >> 4) * 8];
#pragma unroll
            for (int j = 0; j < 4; j++)
                bfv[j] = *(const short8_t*)&Bl[(wc * 64 + j * 16 + (l & 15)) * 72 + kk2 * 32 + (l >> 4) * 8];
#pragma unroll
            for (int i = 0; i < 4; i++)
#pragma unroll
                for (int j = 0; j < 4; j++)
                    acc[i][j] = __builtin_amdgcn_mfma_f32_16x16x32_bf16(af[i], bfv[j], acc[i][j], 0, 0, 0);
        }
        __syncthreads();
    }
    // ---- epilogue ----
#pragma unroll
    for (int i = 0; i < 4; i++)
#pragma unroll
        for (int j = 0; j < 4; j++)
#pragma unroll
            for (int r = 0; r < 4; r++) {
                int m = m0 + wr * 64 + i * 16 + (l >> 4) * 4 + r;
                int n = n0 + wc * 64 + j * 16 + (l & 15);
                float v = acc[i][j][r];
                if constexpr (MODE == 0) {
                    Cbf[(size_t)m * 12800 + n] = f2bf(v);
                } else {
                    if (m < NLAB) {
                        int b = n & 63, s = n >> 6;
                        Cf32[((size_t)b * SEQ + s) * NLAB + m] = v + bias[m];
                    }
                }
            }
}

// ---------------- K4: persistent LSTM ----------------
// 256 blocks x 256 threads.  group g = blockIdx&3 (16 batches), j = blockIdx>>2 (8 h-dims).
// Block owns 32 gate rows {q*512 + j*8 + e}.  Weights live in VGPRs (step-invariant).
// X layout [2048][200][64] bf16, HS layout [200][512][64] bf16.
__global__ __launch_bounds__(256, 1) void lstm_k(const float* __restrict__ Whh,
                                                 const float* __restrict__ bvec,
                                                 const unsigned short* __restrict__ X,
                                                 unsigned short* __restrict__ HS,
                                                 unsigned* __restrict__ cnt) {
    const int g = blockIdx.x & 3;
    const int j = blockIdx.x >> 2;
    const int bQ = g * 16;
    const int tid = threadIdx.x;
    const int p = tid & 3;            // k-slice (4-way)
    const int rt = (tid >> 2) & 15;   // row pair (16)
    const int bt = tid >> 6;          // wave = batch quad (4)

    __shared__ float hl[16][512];
    __shared__ float gatesl[32][20];
    __shared__ float bias_s[32];

    // load weights into registers: 2 rows x 128 k-slice (float4 x 32 each row)
    float4 wreg[2][32];
#pragma unroll
    for (int i = 0; i < 2; i++) {
        int lr = rt * 2 + i;
        int gr = ((lr >> 3) << 9) + j * 8 + (lr & 7);
        const float* wrow = Whh + (size_t)gr * HID + p * 4;
#pragma unroll
        for (int u = 0; u < 32; u++) wreg[i][u] = *(const float4*)(wrow + u * 16);
    }
    if (tid < 32) {
        int gr = ((tid >> 3) << 9) + j * 8 + (tid & 7);
        bias_s[tid] = bvec[gr];
    }
    unsigned* mycnt = cnt + g * 16;

    float cpriv = 0.f;
    const int d = tid >> 4;    // elementwise role (tid<128): h-dim 0..7
    const int lb = tid & 15;   // local batch

    for (int t = 0; t < SEQ; t++) {
        // ---- phase 1: prepare h_{t-1} in LDS ----
        if (t == 0) {
#pragma unroll
            for (int q = 0; q < 32; q++) ((float*)hl)[tid * 32 + q] = 0.f;
        } else {
            if (tid == 0) {
                while (__hip_atomic_load(mycnt, __ATOMIC_ACQUIRE, __HIP_MEMORY_SCOPE_AGENT) <
                       (unsigned)(64 * t)) {
                    __builtin_amdgcn_s_sleep(2);
                }
            }
            __syncthreads();
            __threadfence();  // acquire: invalidate stale cache before reading h
            const unsigned short* hsrc = HS + ((size_t)(t - 1) * HID) * BATCH + bQ;
            int k0 = tid * 2;
#pragma unroll
            for (int kk = 0; kk < 2; kk++) {
                int k = k0 + kk;
                const unsigned short* srcp = hsrc + (size_t)k * BATCH;
                short8_t v0 = *(const short8_t*)srcp;
                short8_t v1 = *(const short8_t*)(srcp + 8);
#pragma unroll
                for (int x = 0; x < 8; x++) {
                    hl[x][k] = bf2f((unsigned short)v0[x]);
                    hl[8 + x][k] = bf2f((unsigned short)v1[x]);
                }
            }
        }
        __syncthreads();

        // ---- phase 2: partial dots (2 rows x 4 batches x 128 k) ----
        float acc[2][4];
#pragma unroll
        for (int i = 0; i < 2; i++)
#pragma unroll
            for (int bb = 0; bb < 4; bb++) acc[i][bb] = 0.f;
#pragma unroll
        for (int u = 0; u < 32; u++) {
            float4 hv[4];
#pragma unroll
            for (int bb = 0; bb < 4; bb++)
                hv[bb] = *(const float4*)&hl[bt * 4 + bb][p * 4 + u * 16];
#pragma unroll
            for (int i = 0; i < 2; i++) {
                float4 wv = wreg[i][u];
#pragma unroll
                for (int bb = 0; bb < 4; bb++) {
                    acc[i][bb] += wv.x * hv[bb].x + wv.y * hv[bb].y + wv.z * hv[bb].z +
                                  wv.w * hv[bb].w;
                }
            }
        }
        // reduce across p (lanes l, l^1, l^2)
#pragma unroll
        for (int i = 0; i < 2; i++)
#pragma unroll
            for (int bb = 0; bb < 4; bb++) {
                float a = acc[i][bb];
                a += __shfl_xor(a, 1);
                a += __shfl_xor(a, 2);
                acc[i][bb] = a;
            }
        if (p == 0) {
#pragma unroll
            for (int i = 0; i < 2; i++) {
                float4 gv;
                gv.x = acc[i][0]; gv.y = acc[i][1]; gv.z = acc[i][2]; gv.w = acc[i][3];
                *(float4*)&gatesl[rt * 2 + i][bt * 4] = gv;
            }
        }
        __syncthreads();

        // ---- phase 3: elementwise LSTM cell (tid<128: 8 dims x 16 batches) ----
        if (tid < 128) {
            float pre[4];
#pragma unroll
            for (int q = 0; q < 4; q++) {
                int gr = q * HID + j * 8 + d;
                float xv = bf2f(X[(size_t)gr * 12800 + t * BATCH + bQ + lb]);
                pre[q] = gatesl[q * 8 + d][lb] + bias_s[q * 8 + d] + xv;
            }
            float ig = sigm(pre[0]);
            float fg = sigm(pre[1]);
            float gg = tanhfast(pre[2]);
            float og = sigm(pre[3]);
            float c = fg * cpriv + ig * gg;
            cpriv = c;
            float h = og * tanhfast(c);
            HS[((size_t)t * HID + j * 8 + d) * BATCH + bQ + lb] = f2bf(h);
        }
        __threadfence();  // release h stores
        __syncthreads();
        if (tid == 0)
            __hip_atomic_fetch_add(mycnt, 1u, __ATOMIC_RELEASE, __HIP_MEMORY_SCOPE_AGENT);
    }
}

// ---------------- K6: CRF forward + scores, one block per batch ----------------
__global__ __launch_bounds__(320) void crf_k(const float* __restrict__ F,
                                             const float* __restrict__ trans,
                                             const int* __restrict__ labels,
                                             const int* __restrict__ lengths,
                                             float* __restrict__ out) {
    const int b = blockIdx.x;
    const int tid = threadIdx.x;
    __shared__ float tl[NLAB * NLAB];
    __shared__ float alpha[2][68];
    __shared__ float fbuf[68];
    __shared__ float red[8];
    __shared__ float norm_s;
    for (int i = tid; i < NLAB * NLAB; i += 320) tl[i] = trans[i];
    const int L = lengths[b];
    const int ii = tid >> 2, jq = tid & 3;
    const int j0 = (jq < 2) ? jq * 17 : 34 + (jq - 2) * 16;
    const int jn = (jq < 2) ? 17 : 16;
    if (tid < NLAB) alpha[0][tid] = (tid == START_L) ? 0.f : -10000.f;
    __syncthreads();
    int p = 0;
    for (int t = 0; t < L; t++) {
        if (tid < NLAB) fbuf[tid] = F[((size_t)b * SEQ + t) * NLAB + tid];
        __syncthreads();
        if (ii < NLAB) {
            float v[17];
            float m = -3.0e38f;
#pragma unroll
            for (int u = 0; u < 17; u++) {
                float x = (u < jn) ? tl[ii * NLAB + j0 + u] + alpha[p][j0 + u] : -3.0e38f;
                v[u] = x;
                m = fmaxf(m, x);
            }
            m = fmaxf(m, __shfl_xor(m, 1));
            m = fmaxf(m, __shfl_xor(m, 2));
            float s = 0.f;
#pragma unroll
            for (int u = 0; u < 17; u++) s += __expf(v[u] - m);
            s += __shfl_xor(s, 1);
            s += __shfl_xor(s, 2);
            if (jq == 0) alpha[p ^ 1][ii] = m + __logf(s) + fbuf[ii];
        }
        __syncthreads();
        p ^= 1;
    }
    // norm = LSE_i(alpha[i] + trans[STOP][i]) using wave 0
    if (tid < 64) {
        float v0 = alpha[p][tid] + tl[STOP_L * NLAB + tid];
        float v1 = (tid + 64 < NLAB) ? alpha[p][tid + 64] + tl[STOP_L * NLAB + tid + 64] : -3.0e38f;
        float m = fmaxf(v0, v1);
#pragma unroll
        for (int off = 1; off < 64; off <<= 1) m = fmaxf(m, __shfl_xor(m, off));
        float s = __expf(v0 - m) + ((tid + 64 < NLAB) ? __expf(v1 - m) : 0.f);
#pragma unroll
        for (int off = 1; off < 64; off <<= 1) s += __shfl_xor(s, off);
        if (tid == 0) norm_s = m + __logf(s);
    }
    // transition + feature scores
    float local = 0.f;
    const int* lab = labels + (size_t)b * SEQ;
    for (int k = tid; k < L; k += 320) {
        int lk = lab[k];
        int prev = (k == 0) ? START_L : lab[k - 1];
        local += tl[lk * NLAB + prev] + F[((size_t)b * SEQ + k) * NLAB + lk];
    }
    if (tid == 0) local += tl[STOP_L * NLAB + lab[L - 1]];
#pragma unroll
    for (int off = 1; off < 64; off <<= 1) local += __shfl_xor(local, off);
    if ((tid & 63) == 0) red[tid >> 6] = local;
    __syncthreads();
    if (tid == 0) {
        float tot = red[0] + red[1] + red[2] + red[3] + red[4];
        out[b] = norm_s - tot;
    }
}

// ---------------- launch ----------------
extern "C" void kernel_launch(void* const* d_in, const int* in_sizes, int n_in,
                              void* d_out, int out_size, void* d_ws, size_t ws_size,
                              hipStream_t stream) {
    const int* data = (const int*)d_in[0];
    const int* lengths = (const int*)d_in[1];
    const int* labels = (const int*)d_in[2];
    const float* emb = (const float*)d_in[3];
    const float* W_ih = (const float*)d_in[4];
    const float* W_hh = (const float*)d_in[5];
    const float* bvec = (const float*)d_in[6];
    const float* W_fc = (const float*)d_in[7];
    const float* b_fc = (const float*)d_in[8];
    const float* trans = (const float*)d_in[9];
    float* out = (float*)d_out;

    // workspace layout (bytes)
    const size_t oA = 0;                 // Aemb bf16 [12800][320]   8,192,000
    const size_t oW = 8192000;           // Wihb bf16 [2048][320]    1,310,720
    const size_t oX = 9502720;           // X bf16 [2048][12800]    52,428,800
    const size_t oHS = 61931520;         // HS bf16 [200][512][64]  13,107,200
    const size_t oF = 75038720;          // F fp32 [64][200][66]     3,379,200
    const size_t oC = 78417920;          // counters                       256
    const size_t need = 78418176;
    if (ws_size < need) return;

    char* w = (char*)d_ws;
    unsigned short* A = (unsigned short*)(w + oA);
    unsigned short* Wb = (unsigned short*)(w + oW);
    unsigned short* X = (unsigned short*)(w + oX);
    unsigned short* HS = (unsigned short*)(w + oHS);
    float* F = (float*)(w + oF);
    unsigned* cnt = (unsigned*)(w + oC);

    hipMemsetAsync(cnt, 0, 256, stream);
    embed_k<<<3200, 256, 0, stream>>>(data, emb, A);
    convw_k<<<2560, 256, 0, stream>>>(W_ih, Wb);
    gemm_k<0><<<1600, 256, 0, stream>>>(Wb, nullptr, A, X, nullptr, nullptr);
    lstm_k<<<256, 256, 0, stream>>>(W_hh, bvec, X, HS, cnt);
    gemm_k<1><<<100, 256, 0, stream>>>(nullptr, W_fc, HS, nullptr, F, b_fc);
    crf_k<<<64, 320, 0, stream>>>(F, trans, labels, lengths, out);
}

// Round 2
// 5299.506 us; speedup vs baseline: 2.3369x; 2.3369x over previous
//
#include <hip/hip_runtime.h>
#include <hip/hip_bf16.h>

// ---------------- common helpers ----------------
typedef __attribute__((ext_vector_type(8))) short short8_t;
typedef __attribute__((ext_vector_type(4))) float f32x4_t;

__device__ __forceinline__ unsigned short f2bf(float f) {
    unsigned u = __float_as_uint(f);
    unsigned r = (u + 0x7FFFu + ((u >> 16) & 1u)) >> 16;
    return (unsigned short)r;
}
__device__ __forceinline__ float bf2f(unsigned short u) {
    return __uint_as_float(((unsigned)u) << 16);
}
__device__ __forceinline__ float sigm(float x) { return 1.f / (1.f + __expf(-x)); }
__device__ __forceinline__ float tanhfast(float x) {
    x = fminf(fmaxf(x, -15.f), 15.f);
    float e = __expf(2.f * x);
    return (e - 1.f) / (e + 1.f);
}

// dims
#define BATCH 64
#define SEQ 200
#define HID 512
#define G4 2048           // 4*HID
#define NLAB 66
#define START_L 64
#define STOP_L 65
#define KPAD 320          // 300 padded to mult of 64

// ---------------- K1: embed gather + max-norm scale -> bf16 A [12800][320] ----------------
__global__ __launch_bounds__(256) void embed_k(const int* __restrict__ data,
                                               const float* __restrict__ emb,
                                               unsigned short* __restrict__ A) {
    int w = threadIdx.x >> 6, l = threadIdx.x & 63;
    int tok = blockIdx.x * 4 + w;
    int s = tok >> 6, b = tok & 63;
    int row = data[b * SEQ + s];
    const float* src = emb + (size_t)row * 300;
    float vals[5];
    float ss = 0.f;
#pragma unroll
    for (int u = 0; u < 5; u++) {
        int e = l + u * 64;
        float v = (e < 300) ? src[e] : 0.f;
        vals[u] = v;
        ss += v * v;
    }
#pragma unroll
    for (int off = 1; off < 64; off <<= 1) ss += __shfl_xor(ss, off);
    float nrm = sqrtf(ss);
    float scale = fminf(1.f, 6.f / fmaxf(nrm, 1e-7f));
    unsigned short* dst = A + (size_t)tok * KPAD;
#pragma unroll
    for (int u = 0; u < 5; u++) {
        int e = l + u * 64;
        dst[e] = (e < 300) ? f2bf(vals[u] * scale) : (unsigned short)0;
    }
}

// ---------------- K2: W_ih fp32[2048][300] -> bf16 [2048][320] ----------------
__global__ void convw_k(const float* __restrict__ W, unsigned short* __restrict__ Wb) {
    int idx = blockIdx.x * blockDim.x + threadIdx.x;
    if (idx < G4 * KPAD) {
        int r = idx / KPAD, k = idx % KPAD;
        Wb[idx] = (k < 300) ? f2bf(W[r * 300 + k]) : (unsigned short)0;
    }
}

// ---------------- K3/K5: MFMA GEMM  C[m][n] = sum_k A[m][k]*B[n][k] ----------------
template <int MODE>
__global__ __launch_bounds__(256) void gemm_k(const unsigned short* __restrict__ Abf,
                                              const float* __restrict__ Af32,
                                              const unsigned short* __restrict__ Bbf,
                                              unsigned short* __restrict__ Cbf,
                                              float* __restrict__ Cf32,
                                              const float* __restrict__ bias) {
    constexpr int KTOT = (MODE == 0) ? KPAD : HID;
    constexpr int NKT = KTOT / 64;
    const int bm = (MODE == 0) ? (blockIdx.x & 15) : 0;
    const int bn = (MODE == 0) ? (blockIdx.x >> 4) : blockIdx.x;
    const int m0 = bm * 128, n0 = bn * 128;
    __shared__ unsigned short Al[128 * 72];
    __shared__ unsigned short Bl[128 * 72];
    const int tid = threadIdx.x;
    const int w = tid >> 6, l = tid & 63;
    const int wr = w >> 1, wc = w & 1;
    f32x4_t acc[4][4];
#pragma unroll
    for (int i = 0; i < 4; i++)
#pragma unroll
        for (int j = 0; j < 4; j++) {
            acc[i][j].x = 0.f; acc[i][j].y = 0.f; acc[i][j].z = 0.f; acc[i][j].w = 0.f;
        }

    for (int kt = 0; kt < NKT; kt++) {
        {
            int row = tid >> 1, half = tid & 1;
            int kbase = kt * 64 + half * 32;
            if constexpr (MODE == 0) {
                const unsigned short* src = Abf + (size_t)(m0 + row) * KPAD + kbase;
#pragma unroll
                for (int q = 0; q < 4; q++)
                    *(short8_t*)&Al[row * 72 + half * 32 + q * 8] = *(const short8_t*)(src + q * 8);
            } else {
                if (row < NLAB) {
                    const float* src = Af32 + (size_t)row * HID + kbase;
#pragma unroll
                    for (int q = 0; q < 4; q++) {
                        short8_t o;
#pragma unroll
                        for (int x = 0; x < 8; x++) o[x] = (short)f2bf(src[q * 8 + x]);
                        *(short8_t*)&Al[row * 72 + half * 32 + q * 8] = o;
                    }
                } else {
                    short8_t z = {0, 0, 0, 0, 0, 0, 0, 0};
#pragma unroll
                    for (int q = 0; q < 4; q++)
                        *(short8_t*)&Al[row * 72 + half * 32 + q * 8] = z;
                }
            }
        }
        if constexpr (MODE == 0) {
            int row = tid >> 1, half = tid & 1;
            int kbase = kt * 64 + half * 32;
            const unsigned short* src = Bbf + (size_t)(n0 + row) * KPAD + kbase;
#pragma unroll
            for (int q = 0; q < 4; q++)
                *(short8_t*)&Bl[row * 72 + half * 32 + q * 8] = *(const short8_t*)(src + q * 8);
        } else {
            int kk = tid >> 2, b0 = (tid & 3) * 16;
            int s0 = n0 >> 6;
#pragma unroll
            for (int sl = 0; sl < 2; sl++) {
                const unsigned short* src =
                    Bbf + ((size_t)(s0 + sl) * HID + kt * 64 + kk) * BATCH + b0;
                short8_t v0 = *(const short8_t*)src;
                short8_t v1 = *(const short8_t*)(src + 8);
#pragma unroll
                for (int x = 0; x < 8; x++) {
                    Bl[(sl * 64 + b0 + x) * 72 + kk] = (unsigned short)v0[x];
                    Bl[(sl * 64 + b0 + 8 + x) * 72 + kk] = (unsigned short)v1[x];
                }
            }
        }
        __syncthreads();
#pragma unroll
        for (int kk2 = 0; kk2 < 2; kk2++) {
            short8_t af[4], bfv[4];
#pragma unroll
            for (int i = 0; i < 4; i++)
                af[i] = *(const short8_t*)&Al[(wr * 64 + i * 16 + (l & 15)) * 72 + kk2 * 32 + (l >> 4) * 8];
#pragma unroll
            for (int j = 0; j < 4; j++)
                bfv[j] = *(const short8_t*)&Bl[(wc * 64 + j * 16 + (l & 15)) * 72 + kk2 * 32 + (l >> 4) * 8];
#pragma unroll
            for (int i = 0; i < 4; i++)
#pragma unroll
                for (int j = 0; j < 4; j++)
                    acc[i][j] = __builtin_amdgcn_mfma_f32_16x16x32_bf16(af[i], bfv[j], acc[i][j], 0, 0, 0);
        }
        __syncthreads();
    }
#pragma unroll
    for (int i = 0; i < 4; i++)
#pragma unroll
        for (int j = 0; j < 4; j++)
#pragma unroll
            for (int r = 0; r < 4; r++) {
                int m = m0 + wr * 64 + i * 16 + (l >> 4) * 4 + r;
                int n = n0 + wc * 64 + j * 16 + (l & 15);
                float v = acc[i][j][r];
                if constexpr (MODE == 0) {
                    Cbf[(size_t)m * 12800 + n] = f2bf(v);
                } else {
                    if (m < NLAB) {
                        int b = n & 63, s = n >> 6;
                        Cf32[((size_t)b * SEQ + s) * NLAB + m] = v + bias[m];
                    }
                }
            }
}

// ---------------- K4: persistent LSTM, fence-free flag sync ----------------
// 256 blocks x 256 threads. group g = blockIdx&3 (16 batches), j = blockIdx>>2 (8 h-dims).
// Block owns 32 gate rows {q*512 + j*8 + e}; W_hh rows live in VGPRs as packed bf16.
// h exchange through agent-scope relaxed atomics (coherent point), per-block flags.
__global__ __launch_bounds__(256, 1) void lstm_k(const float* __restrict__ Whh,
                                                 const float* __restrict__ bvec,
                                                 const unsigned short* __restrict__ X,
                                                 unsigned short* __restrict__ HS,
                                                 unsigned* __restrict__ flags) {
    const int g = blockIdx.x & 3;
    const int j = blockIdx.x >> 2;
    const int bQ = g * 16;
    const int tid = threadIdx.x;
    const int p = tid & 3;            // k-slice (4-way, 128 k each)
    const int rt = (tid >> 2) & 15;   // row pair (16)
    const int bt = tid >> 6;          // wave = batch quad (4)

    __shared__ float hl[16][512];     // [local batch][k]
    __shared__ float gatesl[32][20];
    __shared__ float bias_s[32];

    // ---- load weights into registers as packed bf16: 2 rows x 128 k ----
    unsigned wreg[2][64];
#pragma unroll
    for (int i = 0; i < 2; i++) {
        int lr = rt * 2 + i;
        int gr = ((lr >> 3) << 9) + j * 8 + (lr & 7);
        const float* wrow = Whh + (size_t)gr * HID + p * 4;
#pragma unroll
        for (int u = 0; u < 32; u++) {
            float4 wv = *(const float4*)(wrow + u * 16);
            wreg[i][u * 2] = (unsigned)f2bf(wv.x) | ((unsigned)f2bf(wv.y) << 16);
            wreg[i][u * 2 + 1] = (unsigned)f2bf(wv.z) | ((unsigned)f2bf(wv.w) << 16);
        }
    }
    if (tid < 32) {
        int gr = ((tid >> 3) << 9) + j * 8 + (tid & 7);
        bias_s[tid] = bvec[gr];
    }
    unsigned* gf = flags + g * 64;    // one flag per producer block in this group

    float cpriv = 0.f;
    const int d = tid >> 4;    // elementwise role (tid<128): h-dim 0..7
    const int lb = tid & 15;   // local batch

    for (int t = 0; t < SEQ; t++) {
        // ---- prefetch X gates for this step (latency hidden behind wait) ----
        float xv[4];
        if (tid < 128) {
#pragma unroll
            for (int q = 0; q < 4; q++)
                xv[q] = bf2f(X[(size_t)(q * HID + j * 8 + d) * 12800 + t * BATCH + bQ + lb]);
        }

        // ---- phase 1: h_{t-1} into LDS ----
        if (t == 0) {
#pragma unroll
            for (int q = 0; q < 32; q++) ((float*)hl)[tid * 32 + q] = 0.f;
        } else {
            if (tid < 64) {
                while (__hip_atomic_load(&gf[tid], __ATOMIC_ACQUIRE,
                                         __HIP_MEMORY_SCOPE_AGENT) < (unsigned)t) {
                    __builtin_amdgcn_s_sleep(1);
                }
            }
            __syncthreads();
            // agent-scope loads of h_{t-1}: thread handles k = tid*2+{0,1}, 8 uints (16 batches)
            const unsigned* hsrc =
                (const unsigned*)(HS + (size_t)(t - 1) * HID * BATCH + bQ);
#pragma unroll
            for (int kk = 0; kk < 2; kk++) {
                int k = tid * 2 + kk;
                const unsigned* rp = hsrc + (size_t)k * (BATCH / 2);
                unsigned v[8];
#pragma unroll
                for (int x = 0; x < 8; x++)
                    v[x] = __hip_atomic_load(&rp[x], __ATOMIC_RELAXED,
                                             __HIP_MEMORY_SCOPE_AGENT);
#pragma unroll
                for (int x = 0; x < 8; x++) {
                    hl[2 * x][k] = bf2f((unsigned short)(v[x] & 0xFFFFu));
                    hl[2 * x + 1][k] = bf2f((unsigned short)(v[x] >> 16));
                }
            }
        }
        __syncthreads();

        // ---- phase 2: partial dots (2 rows x 4 batches x 128 k) ----
        float acc[2][4];
#pragma unroll
        for (int i = 0; i < 2; i++)
#pragma unroll
            for (int bb = 0; bb < 4; bb++) acc[i][bb] = 0.f;
#pragma unroll
        for (int u = 0; u < 32; u++) {
            float4 hv[4];
#pragma unroll
            for (int bb = 0; bb < 4; bb++)
                hv[bb] = *(const float4*)&hl[bt * 4 + bb][p * 4 + u * 16];
#pragma unroll
            for (int i = 0; i < 2; i++) {
                unsigned w0 = wreg[i][u * 2], w1 = wreg[i][u * 2 + 1];
                float wx = __uint_as_float(w0 << 16);
                float wy = __uint_as_float(w0 & 0xFFFF0000u);
                float wz = __uint_as_float(w1 << 16);
                float ww = __uint_as_float(w1 & 0xFFFF0000u);
#pragma unroll
                for (int bb = 0; bb < 4; bb++) {
                    acc[i][bb] += wx * hv[bb].x + wy * hv[bb].y + wz * hv[bb].z +
                                  ww * hv[bb].w;
                }
            }
        }
#pragma unroll
        for (int i = 0; i < 2; i++)
#pragma unroll
            for (int bb = 0; bb < 4; bb++) {
                float a = acc[i][bb];
                a += __shfl_xor(a, 1);
                a += __shfl_xor(a, 2);
                acc[i][bb] = a;
            }
        if (p == 0) {
#pragma unroll
            for (int i = 0; i < 2; i++) {
                float4 gv;
                gv.x = acc[i][0]; gv.y = acc[i][1]; gv.z = acc[i][2]; gv.w = acc[i][3];
                *(float4*)&gatesl[rt * 2 + i][bt * 4] = gv;
            }
        }
        __syncthreads();

        // ---- phase 3: elementwise LSTM cell (tid<128: 8 dims x 16 batches) ----
        if (tid < 128) {
            float pre[4];
#pragma unroll
            for (int q = 0; q < 4; q++)
                pre[q] = gatesl[q * 8 + d][lb] + bias_s[q * 8 + d] + xv[q];
            float ig = sigm(pre[0]);
            float fg = sigm(pre[1]);
            float gg = tanhfast(pre[2]);
            float og = sigm(pre[3]);
            float c = fg * cpriv + ig * gg;
            cpriv = c;
            float h = og * tanhfast(c);
            // pack pairs across adjacent batches, agent-scope store to coherent point
            unsigned short hb = f2bf(h);
            unsigned short hb1 = (unsigned short)__shfl_xor((int)hb, 1);
            if ((lb & 1) == 0) {
                unsigned pk = (unsigned)hb | ((unsigned)hb1 << 16);
                unsigned* hout = (unsigned*)(HS + (size_t)t * HID * BATCH);
                __hip_atomic_store(&hout[(size_t)(j * 8 + d) * (BATCH / 2) + (bQ >> 1) + (lb >> 1)],
                                   pk, __ATOMIC_RELAXED, __HIP_MEMORY_SCOPE_AGENT);
            }
        }
        __syncthreads();  // barrier drains each thread's stores (vmcnt 0)
        if (tid == 0)
            __hip_atomic_store(&gf[j], (unsigned)(t + 1), __ATOMIC_RELEASE,
                               __HIP_MEMORY_SCOPE_AGENT);
    }
}

// ---------------- K6: CRF forward + scores, one block per batch ----------------
__global__ __launch_bounds__(320) void crf_k(const float* __restrict__ F,
                                             const float* __restrict__ trans,
                                             const int* __restrict__ labels,
                                             const int* __restrict__ lengths,
                                             float* __restrict__ out) {
    const int b = blockIdx.x;
    const int tid = threadIdx.x;
    __shared__ float tl[NLAB * NLAB];
    __shared__ float alpha[2][68];
    __shared__ float fbuf[68];
    __shared__ float red[8];
    __shared__ float norm_s;
    for (int i = tid; i < NLAB * NLAB; i += 320) tl[i] = trans[i];
    const int L = lengths[b];
    const int ii = tid >> 2, jq = tid & 3;
    const int j0 = (jq < 2) ? jq * 17 : 34 + (jq - 2) * 16;
    const int jn = (jq < 2) ? 17 : 16;
    if (tid < NLAB) alpha[0][tid] = (tid == START_L) ? 0.f : -10000.f;
    __syncthreads();
    int p = 0;
    for (int t = 0; t < L; t++) {
        if (tid < NLAB) fbuf[tid] = F[((size_t)b * SEQ + t) * NLAB + tid];
        __syncthreads();
        if (ii < NLAB) {
            float v[17];
            float m = -3.0e38f;
#pragma unroll
            for (int u = 0; u < 17; u++) {
                float x = (u < jn) ? tl[ii * NLAB + j0 + u] + alpha[p][j0 + u] : -3.0e38f;
                v[u] = x;
                m = fmaxf(m, x);
            }
            m = fmaxf(m, __shfl_xor(m, 1));
            m = fmaxf(m, __shfl_xor(m, 2));
            float s = 0.f;
#pragma unroll
            for (int u = 0; u < 17; u++) s += __expf(v[u] - m);
            s += __shfl_xor(s, 1);
            s += __shfl_xor(s, 2);
            if (jq == 0) alpha[p ^ 1][ii] = m + __logf(s) + fbuf[ii];
        }
        __syncthreads();
        p ^= 1;
    }
    if (tid < 64) {
        float v0 = alpha[p][tid] + tl[STOP_L * NLAB + tid];
        float v1 = (tid + 64 < NLAB) ? alpha[p][tid + 64] + tl[STOP_L * NLAB + tid + 64] : -3.0e38f;
        float m = fmaxf(v0, v1);
#pragma unroll
        for (int off = 1; off < 64; off <<= 1) m = fmaxf(m, __shfl_xor(m, off));
        float s = __expf(v0 - m) + ((tid + 64 < NLAB) ? __expf(v1 - m) : 0.f);
#pragma unroll
        for (int off = 1; off < 64; off <<= 1) s += __shfl_xor(s, off);
        if (tid == 0) norm_s = m + __logf(s);
    }
    float local = 0.f;
    const int* lab = labels + (size_t)b * SEQ;
    for (int k = tid; k < L; k += 320) {
        int lk = lab[k];
        int prev = (k == 0) ? START_L : lab[k - 1];
        local += tl[lk * NLAB + prev] + F[((size_t)b * SEQ + k) * NLAB + lk];
    }
    if (tid == 0) local += tl[STOP_L * NLAB + lab[L - 1]];
#pragma unroll
    for (int off = 1; off < 64; off <<= 1) local += __shfl_xor(local, off);
    if ((tid & 63) == 0) red[tid >> 6] = local;
    __syncthreads();
    if (tid == 0) {
        float tot = red[0] + red[1] + red[2] + red[3] + red[4];
        out[b] = norm_s - tot;
    }
}

// ---------------- launch ----------------
extern "C" void kernel_launch(void* const* d_in, const int* in_sizes, int n_in,
                              void* d_out, int out_size, void* d_ws, size_t ws_size,
                              hipStream_t stream) {
    const int* data = (const int*)d_in[0];
    const int* lengths = (const int*)d_in[1];
    const int* labels = (const int*)d_in[2];
    const float* emb = (const float*)d_in[3];
    const float* W_ih = (const float*)d_in[4];
    const float* W_hh = (const float*)d_in[5];
    const float* bvec = (const float*)d_in[6];
    const float* W_fc = (const float*)d_in[7];
    const float* b_fc = (const float*)d_in[8];
    const float* trans = (const float*)d_in[9];
    float* out = (float*)d_out;

    // workspace layout (bytes)
    const size_t oA = 0;                 // Aemb bf16 [12800][320]   8,192,000
    const size_t oW = 8192000;           // Wihb bf16 [2048][320]    1,310,720
    const size_t oX = 9502720;           // X bf16 [2048][12800]    52,428,800
    const size_t oHS = 61931520;         // HS bf16 [200][512][64]  13,107,200
    const size_t oF = 75038720;          // F fp32 [64][200][66]     3,379,200
    const size_t oC = 78417920;          // flags [4][64] uint          1,024
    const size_t need = 78418944;
    if (ws_size < need) return;

    char* w = (char*)d_ws;
    unsigned short* A = (unsigned short*)(w + oA);
    unsigned short* Wb = (unsigned short*)(w + oW);
    unsigned short* X = (unsigned short*)(w + oX);
    unsigned short* HS = (unsigned short*)(w + oHS);
    float* F = (float*)(w + oF);
    unsigned* flags = (unsigned*)(w + oC);

    hipMemsetAsync(flags, 0, 1024, stream);
    embed_k<<<3200, 256, 0, stream>>>(data, emb, A);
    convw_k<<<2560, 256, 0, stream>>>(W_ih, Wb);
    gemm_k<0><<<1600, 256, 0, stream>>>(Wb, nullptr, A, X, nullptr, nullptr);
    lstm_k<<<256, 256, 0, stream>>>(W_hh, bvec, X, HS, flags);
    gemm_k<1><<<100, 256, 0, stream>>>(nullptr, W_fc, HS, nullptr, F, b_fc);
    crf_k<<<64, 320, 0, stream>>>(F, trans, labels, lengths, out);
}